// Round 1
// baseline (382.925 us; speedup 1.0000x reference)
//
#include <hip/hip_runtime.h>

// Problem constants
#define BB      16384
#define IN_DIM  256
#define NE      32
#define H1D     64
#define H2D     256
#define H3D     128
#define NOUT    128

typedef __bf16 bf16_t;
typedef __bf16 bf16x8  __attribute__((ext_vector_type(8)));
typedef __bf16 bf16x4v __attribute__((ext_vector_type(4)));
typedef float  f32x4   __attribute__((ext_vector_type(4)));

// ---- workspace layout (bytes) ----
#define OFF_XB  ((size_t)0)
#define OFF_W1  (OFF_XB + (size_t)BB*IN_DIM*2)          // xb: [B][256] bf16
#define OFF_W2  (OFF_W1 + (size_t)NE*H1D*IN_DIM*2)      // W1t: [E][64][256]
#define OFF_W3  (OFF_W2 + (size_t)NE*H2D*H1D*2)         // W2t: [E][256][64]
#define OFF_W4  (OFF_W3 + (size_t)NE*H3D*H2D*2)         // W3t: [E][128][256]
#define OFF_W5  (OFF_W4 + (size_t)NE*H1D*H3D*2)         // W4t: [E][64][128]
#define OFF_G   (OFF_W5 + (size_t)NE*NOUT*H1D*2)        // W5t: [E][128][64]
// g: [B][32] fp32 at OFF_G; total ~15.7 MB

// ---------------- prep: x -> bf16 ----------------
__global__ void cvt_x_kernel(const float* __restrict__ x, bf16_t* __restrict__ xb) {
    const size_t i = ((size_t)blockIdx.x * 256 + threadIdx.x) * 4;
    const float4 v = *(const float4*)(x + i);
    bf16x4v o = { (bf16_t)v.x, (bf16_t)v.y, (bf16_t)v.z, (bf16_t)v.w };
    *(bf16x4v*)(xb + i) = o;
}

// ---- prep: W [E][K][N] fp32 -> Wt [E][N][K] bf16, LDS-tiled transpose ----
template<int K, int N>
__global__ void cvt_w_t(const float* __restrict__ W, bf16_t* __restrict__ Wt) {
    __shared__ float tile[64][65];
    const int e  = blockIdx.z;
    const int kt = blockIdx.x * 64;
    const int nt = blockIdx.y * 64;
    const int tx = threadIdx.x & 63;
    const int ty = threadIdx.x >> 6;
    const float* src = W + (size_t)e * K * N;
#pragma unroll
    for (int i = 0; i < 16; i++)
        tile[ty + i*4][tx] = src[(size_t)(kt + ty + i*4) * N + nt + tx];
    __syncthreads();
    bf16_t* dst = Wt + (size_t)e * K * N;
#pragma unroll
    for (int i = 0; i < 16; i++)
        dst[(size_t)(nt + ty + i*4) * K + kt + tx] = (bf16_t)tile[tx][ty + i*4];
}

// ---------------- gating: fp32 softmax(x @ Wg + bg) ----------------
__global__ void gating_kernel(const float* __restrict__ x, const float* __restrict__ Wg,
                              const float* __restrict__ bg, float* __restrict__ g)
{
    __shared__ float sx[8][256];
    const int tid  = threadIdx.x;
    const int row0 = blockIdx.x * 8;
    for (int s = tid; s < 512; s += 256) {
        const int off = s * 4;
        const int rr = off >> 8;
        const int cc = off & 255;
        *(float4*)&sx[rr][cc] = *(const float4*)(x + (size_t)(row0 + rr) * 256 + cc);
    }
    __syncthreads();
    const int wave = tid >> 6;
    const int lane = tid & 63;
    const int e    = lane & 31;
    const int rl   = wave * 2 + (lane >> 5);   // 2 rows per wave, one per half-wave
    float acc = bg[e];
    const float* xr = sx[rl];
#pragma unroll 8
    for (int k = 0; k < 256; k++) acc = fmaf(xr[k], Wg[k * 32 + e], acc);
    float mx = acc;
#pragma unroll
    for (int off = 16; off > 0; off >>= 1) mx = fmaxf(mx, __shfl_xor(mx, off));
    const float ex = __expf(acc - mx);
    float sm = ex;
#pragma unroll
    for (int off = 16; off > 0; off >>= 1) sm += __shfl_xor(sm, off);
    g[(size_t)(row0 + rl) * 32 + e] = ex / sm;
}

// ---------------- MFMA layer: [64 x K] @ [K x N] -> relu -> LDS ----------------
// src: LDS [64][SIN] bf16 (row-major, padded). dst: LDS [64][SOUT].
// Wt: [N][K] bf16 (per-expert base). Wave owns NW n-tiles starting at nbase, all 4 m-tiles.
template<int K, int N, int SIN, int SOUT, int NW, bool RELU>
__device__ __forceinline__ void layer_fwd(const bf16_t* __restrict__ src, bf16_t* __restrict__ dst,
                                          const bf16_t* __restrict__ Wt, const float* __restrict__ bias,
                                          int lane16, int quad, int nbase)
{
    constexpr int KS = K / 32;
    f32x4 acc[NW][4];
#pragma unroll
    for (int t = 0; t < NW; t++)
#pragma unroll
        for (int m = 0; m < 4; m++) acc[t][m] = (f32x4){0.f, 0.f, 0.f, 0.f};

#pragma unroll
    for (int ks = 0; ks < KS; ks++) {
        bf16x8 a[4];
#pragma unroll
        for (int m = 0; m < 4; m++)
            a[m] = *(const bf16x8*)(src + (m * 16 + lane16) * SIN + ks * 32 + quad * 8);
#pragma unroll
        for (int t = 0; t < NW; t++) {
            const int n = (nbase + t) * 16 + lane16;
            bf16x8 b = *(const bf16x8*)(Wt + (size_t)n * K + ks * 32 + quad * 8);
#pragma unroll
            for (int m = 0; m < 4; m++)
                acc[t][m] = __builtin_amdgcn_mfma_f32_16x16x32_bf16(a[m], b, acc[t][m], 0, 0, 0);
        }
    }
#pragma unroll
    for (int t = 0; t < NW; t++) {
        const int n = (nbase + t) * 16 + lane16;
        const float bv = bias[n];
#pragma unroll
        for (int m = 0; m < 4; m++) {
#pragma unroll
            for (int r = 0; r < 4; r++) {
                float v = acc[t][m][r] + bv;
                if (RELU) v = fmaxf(v, 0.f);
                dst[(m * 16 + quad * 4 + r) * SOUT + n] = (bf16_t)v;
            }
        }
    }
}

// ---------------- main: 64-row tile x all 32 experts ----------------
__global__ __launch_bounds__(512, 2) void moe_main(
    const bf16_t* __restrict__ xb,
    const bf16_t* __restrict__ W1t, const bf16_t* __restrict__ W2t,
    const bf16_t* __restrict__ W3t, const bf16_t* __restrict__ W4t,
    const bf16_t* __restrict__ W5t,
    const float* __restrict__ b1, const float* __restrict__ b2,
    const float* __restrict__ b3, const float* __restrict__ b4,
    const float* __restrict__ b5,
    const float* __restrict__ g, float* __restrict__ out)
{
    __shared__ bf16_t sX[64 * 264];   // x tile, stride 264 (pad 8)
    __shared__ bf16_t sA[64 * 136];   // h1 (64w) / h3 (128w)
    __shared__ bf16_t sB[64 * 264];   // h2 (256w) / h4 (64w)
    __shared__ float  sG[64];

    const int tid    = threadIdx.x;
    const int wave   = tid >> 6;
    const int lane   = tid & 63;
    const int lane16 = lane & 15;
    const int quad   = lane >> 4;
    const int b0     = blockIdx.x * 64;

    // stage x tile (once): 64 rows x 256 cols bf16
    {
        const int r  = tid >> 3;
        const int c0 = (tid & 7) * 32;
        const bf16_t* src = xb + (size_t)(b0 + r) * IN_DIM + c0;
        bf16_t* dst = sX + r * 264 + c0;
#pragma unroll
        for (int j = 0; j < 4; j++)
            *(bf16x8*)(dst + j * 8) = *(const bf16x8*)(src + j * 8);
    }

    float oacc[4][4];
#pragma unroll
    for (int m = 0; m < 4; m++)
#pragma unroll
        for (int r = 0; r < 4; r++) oacc[m][r] = 0.f;

    __syncthreads();

    for (int e = 0; e < NE; e++) {
        if (tid < 64) sG[tid] = g[(size_t)(b0 + tid) * NE + e];

        // L1: [64x256]@[256x64] -> sA   (waves 0..3; N=64 -> only 4 n-tiles)
        if (wave < 4)
            layer_fwd<256, 64, 264, 136, 1, true>(sX, sA, W1t + (size_t)e * (H1D * IN_DIM),
                                                  b1 + e * H1D, lane16, quad, wave);
        __syncthreads();
        // L2: [64x64]@[64x256] -> sB
        layer_fwd<64, 256, 136, 264, 2, true>(sA, sB, W2t + (size_t)e * (H2D * H1D),
                                              b2 + e * H2D, lane16, quad, wave * 2);
        __syncthreads();
        // L3: [64x256]@[256x128] -> sA
        layer_fwd<256, 128, 264, 136, 1, true>(sB, sA, W3t + (size_t)e * (H3D * H2D),
                                               b3 + e * H3D, lane16, quad, wave);
        __syncthreads();
        // L4: [64x128]@[128x64] -> sB   (waves 4..7)
        if (wave >= 4)
            layer_fwd<128, 64, 136, 264, 1, true>(sA, sB, W4t + (size_t)e * (H1D * H3D),
                                                  b4 + e * H1D, lane16, quad, wave - 4);
        __syncthreads();
        // L5: [64x64]@[64x128], gated accumulate into registers
        {
            const bf16_t* W5e = W5t + (size_t)e * (NOUT * H1D);
            const float*  b5e = b5 + e * NOUT;
            const int n = wave * 16 + lane16;
            f32x4 acc[4];
#pragma unroll
            for (int m = 0; m < 4; m++) acc[m] = (f32x4){0.f, 0.f, 0.f, 0.f};
#pragma unroll
            for (int ks = 0; ks < 2; ks++) {
                bf16x8 bfrag = *(const bf16x8*)(W5e + (size_t)n * H1D + ks * 32 + quad * 8);
#pragma unroll
                for (int m = 0; m < 4; m++) {
                    bf16x8 a = *(const bf16x8*)(sB + (m * 16 + lane16) * 264 + ks * 32 + quad * 8);
                    acc[m] = __builtin_amdgcn_mfma_f32_16x16x32_bf16(a, bfrag, acc[m], 0, 0, 0);
                }
            }
            const float bv = b5e[n];
#pragma unroll
            for (int m = 0; m < 4; m++) {
#pragma unroll
                for (int r = 0; r < 4; r++) {
                    const float gv = sG[m * 16 + quad * 4 + r];
                    oacc[m][r] += gv * (acc[m][r] + bv);
                }
            }
        }
        __syncthreads();
    }

    const int n = wave * 16 + lane16;
#pragma unroll
    for (int m = 0; m < 4; m++)
#pragma unroll
        for (int r = 0; r < 4; r++)
            out[(size_t)(b0 + m * 16 + quad * 4 + r) * NOUT + n] = oacc[m][r];
}

extern "C" void kernel_launch(void* const* d_in, const int* in_sizes, int n_in,
                              void* d_out, int out_size, void* d_ws, size_t ws_size,
                              hipStream_t stream)
{
    (void)in_sizes; (void)n_in; (void)out_size; (void)ws_size;
    const float* x  = (const float*)d_in[0];
    const float* Wg = (const float*)d_in[1];
    const float* bg = (const float*)d_in[2];
    const float* W1 = (const float*)d_in[3];
    const float* b1 = (const float*)d_in[4];
    const float* W2 = (const float*)d_in[5];
    const float* b2 = (const float*)d_in[6];
    const float* W3 = (const float*)d_in[7];
    const float* b3 = (const float*)d_in[8];
    const float* W4 = (const float*)d_in[9];
    const float* b4 = (const float*)d_in[10];
    const float* W5 = (const float*)d_in[11];
    const float* b5 = (const float*)d_in[12];

    char* ws = (char*)d_ws;
    bf16_t* xb  = (bf16_t*)(ws + OFF_XB);
    bf16_t* W1t = (bf16_t*)(ws + OFF_W1);
    bf16_t* W2t = (bf16_t*)(ws + OFF_W2);
    bf16_t* W3t = (bf16_t*)(ws + OFF_W3);
    bf16_t* W4t = (bf16_t*)(ws + OFF_W4);
    bf16_t* W5t = (bf16_t*)(ws + OFF_W5);
    float*  g   = (float*)(ws + OFF_G);
    float*  out = (float*)d_out;

    cvt_x_kernel<<<dim3(4096), dim3(256), 0, stream>>>(x, xb);
    cvt_w_t<256, 64><<<dim3(4, 1, 32), dim3(256), 0, stream>>>(W1, W1t);
    cvt_w_t<64, 256><<<dim3(1, 4, 32), dim3(256), 0, stream>>>(W2, W2t);
    cvt_w_t<256, 128><<<dim3(4, 2, 32), dim3(256), 0, stream>>>(W3, W3t);
    cvt_w_t<128, 64><<<dim3(2, 1, 32), dim3(256), 0, stream>>>(W4, W4t);
    cvt_w_t<64, 128><<<dim3(1, 2, 32), dim3(256), 0, stream>>>(W5, W5t);
    gating_kernel<<<dim3(2048), dim3(256), 0, stream>>>(x, Wg, bg, g);
    moe_main<<<dim3(256), dim3(512), 0, stream>>>(xb, W1t, W2t, W3t, W4t, W5t,
                                                  b1, b2, b3, b4, b5, g, out);
}